// Round 12
// baseline (361.301 us; speedup 1.0000x reference)
//
#include <hip/hip_runtime.h>

typedef unsigned long long u64;

#define BATCH 16
#define NN 512   // n  (j index, "nxt" side; rows of X)
#define MM 512   // m  (i index, "cur" side; cols of X)
#define DD 128
#define QP_ITERS 20
#define NBLK (BATCH * 16)   // 256 qp blocks, 1 per CU
#define SLOTW 512           // u64 words per block slot: col-paired {x, qx}

// ---------------------------------------------------------------------------
// gemm_q v4: qm[b,j,i] = 0.5*(rc_i + rn_j) - (nc_i.nn_j + ec_i.en_j)
// with row-norms FUSED (accumulated from staging registers, combined via
// LDS reuse) and per-tile q-sums stored plainly (no atomics). Block (0,0,0)
// zeroes the qp flag words (stream-ordered before the cooperative kernel).
// 128(i) x 64(j) tile, BK=16, 512 blocks (2/CU), k-major LDS, 4x8 micro,
// register-prefetch double buffering.  [R10-proven core]
// ---------------------------------------------------------------------------
__global__ __launch_bounds__(256, 2) void gemm_q_kernel(
    const float* __restrict__ nc, const float* __restrict__ ec,
    const float* __restrict__ nn, const float* __restrict__ en,
    float* __restrict__ qm, float* __restrict__ qsums,
    float* __restrict__ q2sums, unsigned* __restrict__ flags)
{
    int b  = blockIdx.z;
    int it = blockIdx.x;             // i tile, 128 wide (0..3)
    int jt = blockIdx.y;             // j tile,  64 wide (0..7)
    int tid = threadIdx.x;
    int tx = tid & 15, ty = tid >> 4;   // micro: 8 i-cols x 4 j-rows

    if (it == 0 && jt == 0 && b == 0) {          // zero qp flags (512 words)
        flags[tid] = 0u; flags[tid + 256] = 0u;
    }

    __shared__ float As[16][64];     // k-major, j rows   (4 KB)
    __shared__ float Bs[16][128];    // k-major, i rows   (8 KB)

    float acc[4][8] = {};            // [j][i]
    float s_a = 0.f, s_b = 0.f;      // row-norm partials from staged regs

    int a_row = tid & 63;            // A: 64 rows x 16k -> 1 float4/thread
    int a_kc  = (tid >> 6) * 4;      // 0,4,8,12
    int b_row = tid & 127;           // B: 128 rows x 16k -> 2 float4/thread
    int b_kc  = (tid >> 7) * 8;      // 0 or 8

    const float* aBase[2] = { nn + ((size_t)b*NN + jt*64)  * DD,
                              en + ((size_t)b*NN + jt*64)  * DD };
    const float* bBase[2] = { nc + ((size_t)b*MM + it*128) * DD,
                              ec + ((size_t)b*MM + it*128) * DD };

    float4 pa  = *(const float4*)(aBase[0] + (size_t)a_row * DD + a_kc);
    float4 pb0 = *(const float4*)(bBase[0] + (size_t)b_row * DD + b_kc);
    float4 pb1 = *(const float4*)(bBase[0] + (size_t)b_row * DD + b_kc + 4);

    for (int stage = 0; stage < 16; ++stage) {
        __syncthreads();
        As[a_kc+0][a_row] = pa.x;  As[a_kc+1][a_row] = pa.y;
        As[a_kc+2][a_row] = pa.z;  As[a_kc+3][a_row] = pa.w;
        s_a += pa.x*pa.x + pa.y*pa.y + pa.z*pa.z + pa.w*pa.w;
        Bs[b_kc+0][b_row] = pb0.x; Bs[b_kc+1][b_row] = pb0.y;
        Bs[b_kc+2][b_row] = pb0.z; Bs[b_kc+3][b_row] = pb0.w;
        Bs[b_kc+4][b_row] = pb1.x; Bs[b_kc+5][b_row] = pb1.y;
        Bs[b_kc+6][b_row] = pb1.z; Bs[b_kc+7][b_row] = pb1.w;
        s_b += pb0.x*pb0.x + pb0.y*pb0.y + pb0.z*pb0.z + pb0.w*pb0.w
             + pb1.x*pb1.x + pb1.y*pb1.y + pb1.z*pb1.z + pb1.w*pb1.w;
        __syncthreads();

        if (stage + 1 < 16) {
            int s   = stage + 1;
            int mat = s >> 3;
            int kb  = (s & 7) * 16;
            pa  = *(const float4*)(aBase[mat] + (size_t)a_row * DD + kb + a_kc);
            pb0 = *(const float4*)(bBase[mat] + (size_t)b_row * DD + kb + b_kc);
            pb1 = *(const float4*)(bBase[mat] + (size_t)b_row * DD + kb + b_kc + 4);
        }

        #pragma unroll
        for (int k = 0; k < 16; ++k) {
            float af[4], bf[8];
            *(float4*)&af[0] = *(const float4*)&As[k][ty*4];
            *(float4*)&bf[0] = *(const float4*)&Bs[k][tx*8];
            *(float4*)&bf[4] = *(const float4*)&Bs[k][tx*8+4];
            #pragma unroll
            for (int r = 0; r < 4; ++r)
                #pragma unroll
                for (int c = 0; c < 8; ++c)
                    acc[r][c] += af[r] * bf[c];
        }
    }

    // ---- combine row-norm partials through reused LDS ----
    __syncthreads();                       // k-loop LDS reads complete
    float* nA = &As[0][0];                 // 256 floats: [kchunk4][jrow64]
    float* nB = &As[4][0];                 // 256 floats: [kchunk2][irow128]
    nA[tid] = s_a;                         // (tid>>6)*64 + a_row == tid
    nB[tid] = s_b;                         // (tid>>7)*128 + b_row == tid
    __syncthreads();

    float rci[8];
    int i0 = it*128 + tx*8;
    #pragma unroll
    for (int c = 0; c < 8; ++c) {
        int il = tx*8 + c;
        rci[c] = nB[il] + nB[128 + il];    // ||nc_i||^2 + ||ec_i||^2
    }

    float qs = 0.f, q2s = 0.f;
    #pragma unroll
    for (int r = 0; r < 4; ++r) {
        int jl = ty*4 + r;
        float rnj = nA[jl] + nA[64+jl] + nA[128+jl] + nA[192+jl];
        int j = jt*64 + jl;
        size_t rowp = ((size_t)b*NN + j)*MM + i0;
        float4 o0, o1;
        float v;
        v = 0.5f*(rci[0] + rnj) - acc[r][0]; o0.x = v; qs += v; q2s += v*v;
        v = 0.5f*(rci[1] + rnj) - acc[r][1]; o0.y = v; qs += v; q2s += v*v;
        v = 0.5f*(rci[2] + rnj) - acc[r][2]; o0.z = v; qs += v; q2s += v*v;
        v = 0.5f*(rci[3] + rnj) - acc[r][3]; o0.w = v; qs += v; q2s += v*v;
        v = 0.5f*(rci[4] + rnj) - acc[r][4]; o1.x = v; qs += v; q2s += v*v;
        v = 0.5f*(rci[5] + rnj) - acc[r][5]; o1.y = v; qs += v; q2s += v*v;
        v = 0.5f*(rci[6] + rnj) - acc[r][6]; o1.z = v; qs += v; q2s += v*v;
        v = 0.5f*(rci[7] + rnj) - acc[r][7]; o1.w = v; qs += v; q2s += v*v;
        *(float4*)(qm + rowp)     = o0;
        *(float4*)(qm + rowp + 4) = o1;
    }

    #pragma unroll
    for (int off = 32; off; off >>= 1) {
        qs  += __shfl_down(qs,  off);
        q2s += __shfl_down(q2s, off);
    }
    __shared__ float red[8];
    int wid = tid >> 6, lane = tid & 63;
    if (lane == 0) { red[wid] = qs; red[4 + wid] = q2s; }
    __syncthreads();
    if (tid == 0) {
        int tile = b * 32 + jt * 4 + it;
        qsums[tile]  = red[0] + red[1] + red[2] + red[3];
        q2sums[tile] = red[4] + red[5] + red[6] + red[7];
    }
}

// ---------------------------------------------------------------------------
// paired gather: 16 u64 {x-partial, qx-partial} words, stride SLOTW.
// ---------------------------------------------------------------------------
__device__ __forceinline__ void gather16_pair(const u64* p, float& cs, float& cq)
{
    cs = 0.f; cq = 0.f;
    #pragma unroll
    for (int g2 = 0; g2 < 16; ++g2) {
        u64 v = __hip_atomic_load(p + g2 * SLOTW, __ATOMIC_RELAXED,
                                  __HIP_MEMORY_SCOPE_AGENT);
        cs += __uint_as_float((unsigned)v);
        cq += __uint_as_float((unsigned)(v >> 32));
    }
}

// ---------------------------------------------------------------------------
// qp_iter_kernel v9: persistent 20-iteration PGD solve. R10-proven flag
// protocol (speculative acquire-probe, acquire-poll fallback, release flag,
// vmcnt-drain via __syncthreads). Exchange slots are col-paired u64 words:
// threads 0-511 reduce + store one 8B word each and gather 16 u64s —
// same bytes as R10, half the memory-issue. Prologue reduces gemm's 32
// per-tile q-sums into lr/s1 (no atomics, no init kernel).
// ---------------------------------------------------------------------------
__global__ __launch_bounds__(1024, 4) void qp_iter_kernel(
    const float* __restrict__ qm, const float* __restrict__ qsums,
    const float* __restrict__ q2sums, u64* __restrict__ part,
    unsigned* __restrict__ flags, float* __restrict__ out)
{
    __shared__ float lds[16384 + 32];        // partial matrices + wred
    __shared__ int sh_ok;
    float* stage = lds;                      // [1024]: 0..511 f, 512..1023 colq
    float* wred  = lds + 16384;              // [16] wave partials for s

    int tid   = threadIdx.x;
    int blk   = blockIdx.x;
    int b     = blk >> 4;            // batch
    int g     = blk & 15;            // row-group: rows g*32..g*32+31
    int w     = tid >> 6;            // wave 0..15
    int lane  = tid & 63;
    int r_loc = tid >> 5;            // 0..31 local row
    int cseg  = tid & 31;            // owns cols cseg + 32k
    int j     = g * 32 + r_loc;

    size_t rowbase = ((size_t)b * NN + j) * MM;

    // ---- prologue: reduce 32 per-tile sums -> lr, s1 ----
    if (w == 0) {
        float v1 = (lane < 32) ? qsums[b * 32 + lane]  : 0.f;
        float v2 = (lane < 32) ? q2sums[b * 32 + lane] : 0.f;
        #pragma unroll
        for (int m = 32; m; m >>= 1) {
            v1 += __shfl_xor(v1, m);
            v2 += __shfl_xor(v2, m);
        }
        if (lane == 0) { wred[0] = v1; wred[1] = v2; }
    }

    float q[16], x[16], fk[16];
    #pragma unroll
    for (int k = 0; k < 16; ++k) q[k] = qm[rowbase + cseg + 32*k];

    const float inv_m = 1.0f / (float)MM;
    #pragma unroll
    for (int k = 0; k < 16; ++k) { x[k] = inv_m; fk[k] = 1.0f; }

    __syncthreads();
    const float lr = 0.5f / (wred[1] + 1e-8f);
    float s = wred[0] * inv_m;       // s1 = sum(qm)/m  (X0 = 1/m)

    unsigned* myflag = flags + b * 32 + g;
    unsigned* bflags = flags + b * 32;

    for (int t = 1; t <= QP_ITERS; ++t) {
        if (t > 1) {
            unsigned tt = (unsigned)(t - 1);
            // ---- speculative probe (acquire) ----
            if (w == 0) {
                unsigned v = (lane < 16)
                    ? __hip_atomic_load(bflags + lane, __ATOMIC_ACQUIRE,
                                        __HIP_MEMORY_SCOPE_AGENT)
                    : tt;
                int ok = __all(v >= tt);
                if (lane == 0) sh_ok = ok;
            }
            __syncthreads();   // broadcast sh_ok; prior lds reads all done

            const u64* p = part + (size_t)((t - 1) & 1) * (NBLK * SLOTW)
                         + (size_t)b * (16 * SLOTW) + tid;
            float cs = 0.f, cq = 0.f;
            if (tid < 512) gather16_pair(p, cs, cq);

            if (!sh_ok) {      // fallback: proven poll + ordered re-gather
                if (w == 0) {
                    for (;;) {
                        unsigned v = (lane < 16)
                            ? __hip_atomic_load(bflags + lane, __ATOMIC_ACQUIRE,
                                                __HIP_MEMORY_SCOPE_AGENT)
                            : tt;
                        if (__all(v >= tt)) break;
                    }
                }
                __syncthreads();
                if (tid < 512) gather16_pair(p, cs, cq);
            }

            if (tid < 512) {
                stage[tid]       = fminf(1.0f, 2.0f / (cs + 1e-8f));   // f
                stage[512 + tid] = cq;                                 // colq
            }
            __syncthreads();
            float v = (tid < 512) ? stage[tid] * stage[512 + tid] : 0.f;
            #pragma unroll
            for (int m = 32; m; m >>= 1) v += __shfl_xor(v, m);
            if (lane == 0) wred[w] = v;
            #pragma unroll
            for (int k = 0; k < 16; ++k) fk[k] = stage[cseg + 32*k];
            __syncthreads();   // wred ready; all stage reads complete
            float sacc = 0.f;
            #pragma unroll
            for (int i = 0; i < 16; ++i) sacc += wred[i];   // LDS broadcast
            s = sacc;
        }

        // ---- gradient step + clip + row normalize ----
        float c = 2.0f * lr * s;
        float rp = 0.f;
        #pragma unroll
        for (int k = 0; k < 16; ++k) {
            float v = x[k] * fk[k] - c * q[k];
            v = fminf(fmaxf(v, 0.f), 1.f);
            x[k] = v;
            rp += v;
        }
        #pragma unroll
        for (int m = 16; m; m >>= 1) rp += __shfl_xor(rp, m);
        float inv = 1.0f / (rp + 1e-8f);
        #pragma unroll
        for (int k = 0; k < 16; ++k) x[k] *= inv;

        // ---- column partial pass ----
        #pragma unroll
        for (int k = 0; k < 16; ++k) {
            float qx = q[k] * x[k];
            float px = x[k] + __shfl_xor(x[k], 32);   // row-pair sum
            float pq = qx   + __shfl_xor(qx,   32);
            int col = cseg + 32*k;
            if (lane < 32) lds[w * 512 + col]        = px;   // x partials
            else           lds[8192 + w * 512 + col] = pq;   // qx partials
        }
        __syncthreads();
        if (tid < 512) {
            int col = tid;
            float ax = 0.f, aq = 0.f;
            #pragma unroll
            for (int w2 = 0; w2 < 16; ++w2) {
                ax += lds[w2 * 512 + col];
                aq += lds[8192 + w2 * 512 + col];
            }
            u64 word = ((u64)__float_as_uint(aq) << 32)
                     | (u64)__float_as_uint(ax);
            u64* dst = part + (size_t)(t & 1) * (NBLK * SLOTW)
                     + (size_t)blk * SLOTW + col;
            __hip_atomic_store(dst, word, __ATOMIC_RELAXED,
                               __HIP_MEMORY_SCOPE_AGENT);
        }

        __syncthreads();   // drain partial stores (vmcnt 0) before release
        if (tid == 0)
            __hip_atomic_store(myflag, (unsigned)t, __ATOMIC_RELEASE,
                               __HIP_MEMORY_SCOPE_AGENT);
    }

    // ---- final: poll iteration 20's flags, gather, lazy scale, store ----
    {
        unsigned tt = (unsigned)QP_ITERS;
        if (w == 0) {
            for (;;) {
                unsigned v = (lane < 16)
                    ? __hip_atomic_load(bflags + lane, __ATOMIC_ACQUIRE,
                                        __HIP_MEMORY_SCOPE_AGENT)
                    : tt;
                if (__all(v >= tt)) break;
            }
        }
        __syncthreads();
        if (tid < 512) {
            const u64* p = part + (size_t)(QP_ITERS & 1) * (NBLK * SLOTW)
                         + (size_t)b * (16 * SLOTW) + tid;
            float cs, cq;
            gather16_pair(p, cs, cq);
            stage[tid] = fminf(1.0f, 2.0f / (cs + 1e-8f));
        }
        __syncthreads();
        #pragma unroll
        for (int k = 0; k < 16; ++k)
            out[rowbase + cseg + 32*k] = x[k] * stage[cseg + 32*k];
    }
}

// ---------------------------------------------------------------------------
extern "C" void kernel_launch(void* const* d_in, const int* in_sizes, int n_in,
                              void* d_out, int out_size, void* d_ws, size_t ws_size,
                              hipStream_t stream)
{
    const float* nc = (const float*)d_in[0];  // n_emb_cur (16,512,128)
    const float* ec = (const float*)d_in[1];  // e_emb_cur
    const float* nn = (const float*)d_in[2];  // n_emb_nxt
    const float* en = (const float*)d_in[3];  // e_emb_nxt
    float* out = (float*)d_out;               // (16, 512*512) fp32

    float* ws = (float*)d_ws;
    const size_t QM_FLOATS = (size_t)BATCH * NN * MM;       // 4,194,304 (16 MB)

    float* qm  = ws;
    u64* part  = (u64*)(ws + QM_FLOATS);                    // 2*NBLK*SLOTW u64 (2 MB)
    float* qsums  = (float*)(part + (size_t)2 * NBLK * SLOTW);  // 512
    float* q2sums = qsums + 512;                                // 512
    unsigned* flags = (unsigned*)(q2sums + 512);                // 512 words

    gemm_q_kernel<<<dim3(4, 8, BATCH), 256, 0, stream>>>(nc, ec, nn, en, qm,
                                                         qsums, q2sums, flags);

    void* args[] = { (void*)&qm, (void*)&qsums, (void*)&q2sums,
                     (void*)&part, (void*)&flags, (void*)&out };
    hipLaunchCooperativeKernel((const void*)qp_iter_kernel,
                               dim3(NBLK), dim3(1024),
                               args, 0, stream);
}

// Round 13
// 326.105 us; speedup vs baseline: 1.1079x; 1.1079x over previous
//
#include <hip/hip_runtime.h>

#define BATCH 16
#define NN 512   // n  (j index, "nxt" side; rows of X)
#define MM 512   // m  (i index, "cur" side; cols of X)
#define DD 128
#define QP_ITERS 20
#define NBLK (BATCH * 16)   // 256 qp blocks; 2-blocks/CU capacity => all resident
#define SLOT 1024           // floats per block slot (512 x-partials + 512 qx)

// ---------------------------------------------------------------------------
// gemm_q v4 (R12-proven): qm = 0.5*(rc_i + rn_j) - (nc_i.nn_j + ec_i.en_j)
// row-norms fused from staging registers; per-tile q-sums plain-stored;
// block (0,0,0) zeroes the qp flag words (stream-ordered before qp kernel).
// 128(i) x 64(j) tile, BK=16, 512 blocks (2/CU), k-major LDS, 4x8 micro,
// register-prefetch double buffering.
// ---------------------------------------------------------------------------
__global__ __launch_bounds__(256, 2) void gemm_q_kernel(
    const float* __restrict__ nc, const float* __restrict__ ec,
    const float* __restrict__ nn, const float* __restrict__ en,
    float* __restrict__ qm, float* __restrict__ qsums,
    float* __restrict__ q2sums, unsigned* __restrict__ flags)
{
    int b  = blockIdx.z;
    int it = blockIdx.x;             // i tile, 128 wide (0..3)
    int jt = blockIdx.y;             // j tile,  64 wide (0..7)
    int tid = threadIdx.x;
    int tx = tid & 15, ty = tid >> 4;   // micro: 8 i-cols x 4 j-rows

    if (it == 0 && jt == 0 && b == 0) {          // zero qp flags (512 words)
        flags[tid] = 0u; flags[tid + 256] = 0u;
    }

    __shared__ float As[16][64];     // k-major, j rows   (4 KB)
    __shared__ float Bs[16][128];    // k-major, i rows   (8 KB)

    float acc[4][8] = {};            // [j][i]
    float s_a = 0.f, s_b = 0.f;      // row-norm partials from staged regs

    int a_row = tid & 63;            // A: 64 rows x 16k -> 1 float4/thread
    int a_kc  = (tid >> 6) * 4;      // 0,4,8,12
    int b_row = tid & 127;           // B: 128 rows x 16k -> 2 float4/thread
    int b_kc  = (tid >> 7) * 8;      // 0 or 8

    const float* aBase[2] = { nn + ((size_t)b*NN + jt*64)  * DD,
                              en + ((size_t)b*NN + jt*64)  * DD };
    const float* bBase[2] = { nc + ((size_t)b*MM + it*128) * DD,
                              ec + ((size_t)b*MM + it*128) * DD };

    float4 pa  = *(const float4*)(aBase[0] + (size_t)a_row * DD + a_kc);
    float4 pb0 = *(const float4*)(bBase[0] + (size_t)b_row * DD + b_kc);
    float4 pb1 = *(const float4*)(bBase[0] + (size_t)b_row * DD + b_kc + 4);

    for (int stage = 0; stage < 16; ++stage) {
        __syncthreads();
        As[a_kc+0][a_row] = pa.x;  As[a_kc+1][a_row] = pa.y;
        As[a_kc+2][a_row] = pa.z;  As[a_kc+3][a_row] = pa.w;
        s_a += pa.x*pa.x + pa.y*pa.y + pa.z*pa.z + pa.w*pa.w;
        Bs[b_kc+0][b_row] = pb0.x; Bs[b_kc+1][b_row] = pb0.y;
        Bs[b_kc+2][b_row] = pb0.z; Bs[b_kc+3][b_row] = pb0.w;
        Bs[b_kc+4][b_row] = pb1.x; Bs[b_kc+5][b_row] = pb1.y;
        Bs[b_kc+6][b_row] = pb1.z; Bs[b_kc+7][b_row] = pb1.w;
        s_b += pb0.x*pb0.x + pb0.y*pb0.y + pb0.z*pb0.z + pb0.w*pb0.w
             + pb1.x*pb1.x + pb1.y*pb1.y + pb1.z*pb1.z + pb1.w*pb1.w;
        __syncthreads();

        if (stage + 1 < 16) {
            int s   = stage + 1;
            int mat = s >> 3;
            int kb  = (s & 7) * 16;
            pa  = *(const float4*)(aBase[mat] + (size_t)a_row * DD + kb + a_kc);
            pb0 = *(const float4*)(bBase[mat] + (size_t)b_row * DD + kb + b_kc);
            pb1 = *(const float4*)(bBase[mat] + (size_t)b_row * DD + kb + b_kc + 4);
        }

        #pragma unroll
        for (int k = 0; k < 16; ++k) {
            float af[4], bf[8];
            *(float4*)&af[0] = *(const float4*)&As[k][ty*4];
            *(float4*)&bf[0] = *(const float4*)&Bs[k][tx*8];
            *(float4*)&bf[4] = *(const float4*)&Bs[k][tx*8+4];
            #pragma unroll
            for (int r = 0; r < 4; ++r)
                #pragma unroll
                for (int c = 0; c < 8; ++c)
                    acc[r][c] += af[r] * bf[c];
        }
    }

    // ---- combine row-norm partials through reused LDS ----
    __syncthreads();                       // k-loop LDS reads complete
    float* nA = &As[0][0];                 // 256 floats: [kchunk4][jrow64]
    float* nB = &As[4][0];                 // 256 floats: [kchunk2][irow128]
    nA[tid] = s_a;
    nB[tid] = s_b;
    __syncthreads();

    float rci[8];
    int i0 = it*128 + tx*8;
    #pragma unroll
    for (int c = 0; c < 8; ++c) {
        int il = tx*8 + c;
        rci[c] = nB[il] + nB[128 + il];    // ||nc_i||^2 + ||ec_i||^2
    }

    float qs = 0.f, q2s = 0.f;
    #pragma unroll
    for (int r = 0; r < 4; ++r) {
        int jl = ty*4 + r;
        float rnj = nA[jl] + nA[64+jl] + nA[128+jl] + nA[192+jl];
        int j = jt*64 + jl;
        size_t rowp = ((size_t)b*NN + j)*MM + i0;
        float4 o0, o1;
        float v;
        v = 0.5f*(rci[0] + rnj) - acc[r][0]; o0.x = v; qs += v; q2s += v*v;
        v = 0.5f*(rci[1] + rnj) - acc[r][1]; o0.y = v; qs += v; q2s += v*v;
        v = 0.5f*(rci[2] + rnj) - acc[r][2]; o0.z = v; qs += v; q2s += v*v;
        v = 0.5f*(rci[3] + rnj) - acc[r][3]; o0.w = v; qs += v; q2s += v*v;
        v = 0.5f*(rci[4] + rnj) - acc[r][4]; o1.x = v; qs += v; q2s += v*v;
        v = 0.5f*(rci[5] + rnj) - acc[r][5]; o1.y = v; qs += v; q2s += v*v;
        v = 0.5f*(rci[6] + rnj) - acc[r][6]; o1.z = v; qs += v; q2s += v*v;
        v = 0.5f*(rci[7] + rnj) - acc[r][7]; o1.w = v; qs += v; q2s += v*v;
        *(float4*)(qm + rowp)     = o0;
        *(float4*)(qm + rowp + 4) = o1;
    }

    #pragma unroll
    for (int off = 32; off; off >>= 1) {
        qs  += __shfl_down(qs,  off);
        q2s += __shfl_down(q2s, off);
    }
    __shared__ float red[8];
    int wid = tid >> 6, lane = tid & 63;
    if (lane == 0) { red[wid] = qs; red[4 + wid] = q2s; }
    __syncthreads();
    if (tid == 0) {
        int tile = b * 32 + jt * 4 + it;
        qsums[tile]  = red[0] + red[1] + red[2] + red[3];
        q2sums[tile] = red[4] + red[5] + red[6] + red[7];
    }
}

// ---------------------------------------------------------------------------
__device__ __forceinline__ float gather16_sum_agent(const float* p)
{
    float acc = 0.f;
    #pragma unroll
    for (int g2 = 0; g2 < 16; ++g2)
        acc += __hip_atomic_load((float*)(p + g2 * SLOT), __ATOMIC_RELAXED,
                                 __HIP_MEMORY_SCOPE_AGENT);
    return acc;
}

// ---------------------------------------------------------------------------
// qp_iter_kernel v10: R9/R10-proven persistent PGD solve (f32 exchange,
// speculative probe + poll fallback, release flag) with R12's qsums
// prologue. Launched as a NORMAL kernel: 256 blocks x 1024 thr, 66 KB LDS,
// 56 VGPR -> 2 blocks/CU capacity (512) >= 256, so all blocks are
// co-resident by construction; hand-rolled flag sync needs nothing more.
// ---------------------------------------------------------------------------
__global__ __launch_bounds__(1024, 4) void qp_iter_kernel(
    const float* __restrict__ qm, const float* __restrict__ qsums,
    const float* __restrict__ q2sums, float* __restrict__ part,
    unsigned* __restrict__ flags, float* __restrict__ out)
{
    __shared__ float lds[16384 + 32];        // partial matrices + wred
    __shared__ int sh_ok;
    float* stage = lds;                      // [1024]: 0..511 f, 512..1023 colq
    float* wred  = lds + 16384;              // [16] wave partials for s

    int tid   = threadIdx.x;
    int blk   = blockIdx.x;
    int b     = blk >> 4;            // batch
    int g     = blk & 15;            // row-group: rows g*32..g*32+31
    int w     = tid >> 6;            // wave 0..15
    int lane  = tid & 63;
    int r_loc = tid >> 5;            // 0..31 local row
    int cseg  = tid & 31;            // owns cols cseg + 32k
    int j     = g * 32 + r_loc;

    size_t rowbase = ((size_t)b * NN + j) * MM;

    // ---- prologue: reduce 32 per-tile sums -> lr, s1 ----
    if (w == 0) {
        float v1 = (lane < 32) ? qsums[b * 32 + lane]  : 0.f;
        float v2 = (lane < 32) ? q2sums[b * 32 + lane] : 0.f;
        #pragma unroll
        for (int m = 32; m; m >>= 1) {
            v1 += __shfl_xor(v1, m);
            v2 += __shfl_xor(v2, m);
        }
        if (lane == 0) { wred[0] = v1; wred[1] = v2; }
    }

    float q[16], x[16], fk[16];
    #pragma unroll
    for (int k = 0; k < 16; ++k) q[k] = qm[rowbase + cseg + 32*k];

    const float inv_m = 1.0f / (float)MM;
    #pragma unroll
    for (int k = 0; k < 16; ++k) { x[k] = inv_m; fk[k] = 1.0f; }

    __syncthreads();
    const float lr = 0.5f / (wred[1] + 1e-8f);
    float s = wred[0] * inv_m;       // s1 = sum(qm)/m  (X0 = 1/m)

    unsigned* myflag = flags + b * 32 + g;
    unsigned* bflags = flags + b * 32;

    for (int t = 1; t <= QP_ITERS; ++t) {
        if (t > 1) {
            unsigned tt = (unsigned)(t - 1);
            // ---- speculative probe (acquire) ----
            if (w == 0) {
                unsigned v = (lane < 16)
                    ? __hip_atomic_load(bflags + lane, __ATOMIC_ACQUIRE,
                                        __HIP_MEMORY_SCOPE_AGENT)
                    : tt;
                int ok = __all(v >= tt);
                if (lane == 0) sh_ok = ok;
            }
            __syncthreads();   // broadcast sh_ok; prior lds reads all done

            const float* p = part + (size_t)((t - 1) & 1) * (NBLK * SLOT)
                           + (size_t)b * (16 * SLOT) + tid;
            float acc = gather16_sum_agent(p);

            if (!sh_ok) {      // fallback: proven poll + ordered re-gather
                if (w == 0) {
                    for (;;) {
                        unsigned v = (lane < 16)
                            ? __hip_atomic_load(bflags + lane, __ATOMIC_ACQUIRE,
                                                __HIP_MEMORY_SCOPE_AGENT)
                            : tt;
                        if (__all(v >= tt)) break;
                    }
                }
                __syncthreads();
                acc = gather16_sum_agent(p);
            }

            if (tid < 512) stage[tid] = fminf(1.0f, 2.0f / (acc + 1e-8f)); // f
            else           stage[tid] = acc;                               // colq
            __syncthreads();
            float v = (tid < 512) ? stage[tid] * stage[512 + tid] : 0.f;
            #pragma unroll
            for (int m = 32; m; m >>= 1) v += __shfl_xor(v, m);
            if (lane == 0) wred[w] = v;
            #pragma unroll
            for (int k = 0; k < 16; ++k) fk[k] = stage[cseg + 32*k];
            __syncthreads();   // wred ready; all stage reads complete
            float sacc = 0.f;
            #pragma unroll
            for (int i = 0; i < 16; ++i) sacc += wred[i];   // LDS broadcast
            s = sacc;
        }

        // ---- gradient step + clip + row normalize ----
        float c = 2.0f * lr * s;
        float rp = 0.f;
        #pragma unroll
        for (int k = 0; k < 16; ++k) {
            float v = x[k] * fk[k] - c * q[k];
            v = fminf(fmaxf(v, 0.f), 1.f);
            x[k] = v;
            rp += v;
        }
        #pragma unroll
        for (int m = 16; m; m >>= 1) rp += __shfl_xor(rp, m);
        float inv = 1.0f / (rp + 1e-8f);
        #pragma unroll
        for (int k = 0; k < 16; ++k) x[k] *= inv;

        // ---- column partial pass ----
        #pragma unroll
        for (int k = 0; k < 16; ++k) {
            float qx = q[k] * x[k];
            float px = x[k] + __shfl_xor(x[k], 32);   // row-pair sum
            float pq = qx   + __shfl_xor(qx,   32);
            int col = cseg + 32*k;
            if (lane < 32) lds[w * 512 + col]        = px;   // x partials
            else           lds[8192 + w * 512 + col] = pq;   // qx partials
        }
        __syncthreads();
        {
            int arr = tid >> 9;          // 0 => colsum(x), 1 => colsum(qx)
            int col = tid & 511;
            const float* basep = lds + arr * 8192 + col;
            float acc = 0.f;
            #pragma unroll
            for (int w2 = 0; w2 < 16; ++w2) acc += basep[w2 * 512];
            float* dst = part + (size_t)(t & 1) * (NBLK * SLOT)
                       + (size_t)blk * SLOT + tid;
            __hip_atomic_store(dst, acc, __ATOMIC_RELAXED,
                               __HIP_MEMORY_SCOPE_AGENT);
        }

        __syncthreads();   // drain every thread's partial store (vmcnt 0)
        if (tid == 0)
            __hip_atomic_store(myflag, (unsigned)t, __ATOMIC_RELEASE,
                               __HIP_MEMORY_SCOPE_AGENT);
    }

    // ---- final: poll iteration 20's flags, gather colsum, scale, store ----
    {
        unsigned tt = (unsigned)QP_ITERS;
        if (w == 0) {
            for (;;) {
                unsigned v = (lane < 16)
                    ? __hip_atomic_load(bflags + lane, __ATOMIC_ACQUIRE,
                                        __HIP_MEMORY_SCOPE_AGENT)
                    : tt;
                if (__all(v >= tt)) break;
            }
        }
        __syncthreads();
        const float* p = part + (size_t)(QP_ITERS & 1) * (NBLK * SLOT)
                       + (size_t)b * (16 * SLOT) + tid;   // tid<512: x-partials
        if (tid < 512) {
            float acc = gather16_sum_agent(p);
            stage[tid] = fminf(1.0f, 2.0f / (acc + 1e-8f));
        }
        __syncthreads();
        #pragma unroll
        for (int k = 0; k < 16; ++k)
            out[rowbase + cseg + 32*k] = x[k] * stage[cseg + 32*k];
    }
}

// ---------------------------------------------------------------------------
extern "C" void kernel_launch(void* const* d_in, const int* in_sizes, int n_in,
                              void* d_out, int out_size, void* d_ws, size_t ws_size,
                              hipStream_t stream)
{
    const float* nc = (const float*)d_in[0];  // n_emb_cur (16,512,128)
    const float* ec = (const float*)d_in[1];  // e_emb_cur
    const float* nn = (const float*)d_in[2];  // n_emb_nxt
    const float* en = (const float*)d_in[3];  // e_emb_nxt
    float* out = (float*)d_out;               // (16, 512*512) fp32

    float* ws = (float*)d_ws;
    const size_t QM_FLOATS = (size_t)BATCH * NN * MM;       // 4,194,304 (16 MB)

    float* qm   = ws;
    float* part = ws + QM_FLOATS;                           // 2*NBLK*SLOT floats
    float* qsums  = part + (size_t)2 * NBLK * SLOT;         // 512
    float* q2sums = qsums + 512;                            // 512
    unsigned* flags = (unsigned*)(q2sums + 512);            // 512 words

    gemm_q_kernel<<<dim3(4, 8, BATCH), 256, 0, stream>>>(nc, ec, nn, en, qm,
                                                         qsums, q2sums, flags);

    // NORMAL launch: capacity (2 blocks/CU x 256 CUs) >= 256 blocks ensures
    // co-residency; all inter-block sync is hand-rolled flag spins.
    qp_iter_kernel<<<dim3(NBLK), dim3(1024), 0, stream>>>(
        qm, qsums, q2sums, part, flags, out);
}